// Round 12
// baseline (445.966 us; speedup 1.0000x reference)
//
#include <hip/hip_runtime.h>
#include <stdint.h>

#define B_ 4
#define S_ 2048
#define D_ 256
#define NH_ 12
#define M_ (B_*S_)      // 8192 rows of flattened input
#define J_ (NH_*D_)     // 3072 projection cols
#define LOG2E_ 1.4426950408889634f

typedef __bf16 bf16;
typedef __bf16 bf16x8 __attribute__((ext_vector_type(8)));
typedef __bf16 bf16x4 __attribute__((ext_vector_type(4)));
typedef float  f32x4  __attribute__((ext_vector_type(4)));

#define MFMA16(a,b,c) __builtin_amdgcn_mfma_f32_16x16x32_bf16(a,b,c,0,0,0)

__device__ __forceinline__ void g2lds16(void* l, const void* g) {
  __builtin_amdgcn_global_load_lds(
      (const __attribute__((address_space(1))) unsigned int*)g,
      (__attribute__((address_space(3))) unsigned int*)l, 16, 0, 0);
}

// ---------- prep: X fp32->bf16 (blocks 0..2047) + weight transpose (2048..2431) ----------
__global__ __launch_bounds__(256) void prep_k(const float* __restrict__ X,
                                              bf16* __restrict__ Xbf,
                                              const float* __restrict__ Wqk,
                                              bf16* __restrict__ Wqkt,
                                              const float* __restrict__ Wv,
                                              bf16* __restrict__ Wvt) {
  int bid = blockIdx.x;
  if (bid < 2048) {
    int i = bid * 256 + threadIdx.x;
    f32x4 v = *(const f32x4*)(X + (size_t)i * 4);
    bf16x4 o;
#pragma unroll
    for (int k = 0; k < 4; ++k) o[k] = (bf16)v[k];
    *(bf16x4*)(Xbf + (size_t)i * 4) = o;
  } else {
    int q = bid - 2048;                        // 0..383 = z*192 + y*12 + x
    const float* W = (q >= 192) ? Wv : Wqk;
    bf16* Wt       = (q >= 192) ? Wvt : Wqkt;
    q %= 192;
    int c0 = (q / 12) * 16;
    int j  = (q % 12) * 256 + threadIdx.x;     // coalesced over j
    bf16x8 v0, v1;
#pragma unroll
    for (int i = 0; i < 8; ++i) v0[i] = (bf16)W[(size_t)(c0 + i) * J_ + j];
#pragma unroll
    for (int i = 0; i < 8; ++i) v1[i] = (bf16)W[(size_t)(c0 + 8 + i) * J_ + j];
    *(bf16x8*)(Wt + (size_t)j * D_ + c0)     = v0;
    *(bf16x8*)(Wt + (size_t)j * D_ + c0 + 8) = v1;
  }
}

// ---------------- mask tile flags body: 1 if 64x64 tile is all ones ----------------
__device__ __forceinline__ void mask_flags_body(const int* __restrict__ mask,
                                                int* __restrict__ flags, int bx) {
  int ft = bx & 31, st = (bx >> 5) & 31, b = bx >> 10;
  int t = threadIdx.x;
  const int4* mp4 = (const int4*)(mask + (size_t)b * S_ * S_ +
                                  (size_t)(st * 64 + (t >> 2)) * S_ + ft * 64 + (t & 3) * 16);
  bool ok = true;
#pragma unroll
  for (int i = 0; i < 4; ++i) {
    int4 v = mp4[i];
    ok &= (v.x == 1) & (v.y == 1) & (v.z == 1) & (v.w == 1);
  }
  __shared__ int flag;
  if (t == 0) flag = 1;
  __syncthreads();
  if (!ok) flag = 0;                   // benign race, all write 0
  __syncthreads();
  if (t == 0) flags[bx] = flag;
}

// ---------------- GEMM body: C[M][N] = (A[M][256] * Bm[N][256]^T + bias)*scale --------
// 128x128 tile, BK=64, 4 waves each 64x64. XOR 8-chunk swizzle -> 2-way banks.
// R15: double-buffered LDS + 1-iter prefetch. R18: scale folds log2e for QK.
__device__ __forceinline__ void gemm_body(
    const bf16* __restrict__ A, const bf16* __restrict__ Bm,
    const float* __restrict__ bias, bf16* __restrict__ C,
    int Ndim, int bias_mode, float scale, int bid)
{
  __shared__ bf16 As[2][128 * 64];
  __shared__ bf16 Bs[2][128 * 64];
  const int nbn = Ndim >> 7;
  const int bm = bid / nbn, bn = bid % nbn;
  const int t = threadIdx.x, w = t >> 6, l = t & 63;
  const int lane16 = l & 15, quad = l >> 4;
  const int wm = (w & 1) << 6, wn = (w >> 1) << 6;
  const int srow = t >> 3;
  const int gc = (t & 7) ^ (srow & 7);
  const bf16* Ag = A + (size_t)((bm << 7) + srow) * 256 + gc * 8;
  const bf16* Bg = Bm + (size_t)((bn << 7) + srow) * 256 + gc * 8;

  auto stage = [&](int buf, int k0) {
#pragma unroll
    for (int i = 0; i < 4; ++i)
      g2lds16(&As[buf][(size_t)(i * 256 + (w << 6)) * 8], Ag + (size_t)i * 32 * 256 + k0);
#pragma unroll
    for (int i = 0; i < 4; ++i)
      g2lds16(&Bs[buf][(size_t)(i * 256 + (w << 6)) * 8], Bg + (size_t)i * 32 * 256 + k0);
  };

  f32x4 acc[4][4] = {};
  stage(0, 0);                          // prologue prefetch
  int cur = 0;
  for (int k0 = 0; k0 < 256; k0 += 64) {
    __syncthreads();                    // drains DMA(cur) issued one iter ago
    if (k0 + 64 < 256) stage(cur ^ 1, k0 + 64);  // prefetch under compute
#pragma unroll
    for (int kt = 0; kt < 2; ++kt) {
      bf16x8 af[4], bfr[4];
#pragma unroll
      for (int i = 0; i < 4; ++i)
        af[i] = *(const bf16x8*)(&As[cur][(wm + i * 16 + lane16) * 64 +
                                 (((kt * 4 + quad) ^ (lane16 & 7)) * 8)]);
#pragma unroll
      for (int i = 0; i < 4; ++i)
        bfr[i] = *(const bf16x8*)(&Bs[cur][(wn + i * 16 + lane16) * 64 +
                                  (((kt * 4 + quad) ^ (lane16 & 7)) * 8)]);
#pragma unroll
      for (int i = 0; i < 4; ++i)
#pragma unroll
        for (int jx = 0; jx < 4; ++jx)
          acc[i][jx] = MFMA16(af[i], bfr[jx], acc[i][jx]);
    }
    cur ^= 1;
  }
#pragma unroll
  for (int i = 0; i < 4; ++i)
#pragma unroll
    for (int jx = 0; jx < 4; ++jx) {
      int col = (bn << 7) + wn + jx * 16 + lane16;
#pragma unroll
      for (int r = 0; r < 4; ++r) {
        int row = (bm << 7) + wm + i * 16 + quad * 4 + r;
        float v = (acc[i][jx][r] + (bias_mode ? bias[row] : bias[col])) * scale;
        C[(size_t)row * Ndim + col] = (bf16)v;
      }
    }
}

// R17: both projections + mask_flags in ONE dispatch.
__global__ __launch_bounds__(256) void gemm_flags(
    const bf16* __restrict__ Xbf, const bf16* __restrict__ Wqkt,
    const float* __restrict__ bqk, bf16* __restrict__ QKw,
    const bf16* __restrict__ Wvt, const float* __restrict__ bv,
    bf16* __restrict__ Vtw,
    const int* __restrict__ mask, int* __restrict__ flags)
{
  int bid = blockIdx.x;
  if (bid < 1536)      gemm_body(Xbf, Wqkt, bqk, QKw, J_, 0, LOG2E_, bid);
  else if (bid < 3072) gemm_body(Wvt, Xbf, bv, Vtw, M_, 1, 1.0f, bid - 1536);
  else                 mask_flags_body(mask, flags, bid - 3072);
}

// ---------------- fused attention ----------------
// R20 RESTRUCTURE (3rd submission R22 — R10/R11 benches died at container
// acquire, no timing fields = infra, kernel never ran; audit x3 clean): one
// 512-thread 8-wave block per 128-row s-tile, KVBLK=64 -> 16 iterations (was
// 2x 4-wave blocks, KVBLK=32, 32 iters). Same total MFMA/LDS/DMA work, HALF
// the lockstep barrier events. Rationale: attn pinned at ~256us across 3
// pipe-mix variants (R5/R7/R9) with NO pipe saturated -> latency/lockstep-
// bound. Waves/CU can't rise (register file), so halve sync frequency.
// QK: waves = 4 s-groups x 2 f-halves (wsg=w&3, wfh=w>>2). PV d-split over
// 8 waves (32 d each) -> oacc HALVES to 64 AGPRs (~190 regs, off the R6/R7
// 256-reg cliff). Ps block tile [128][72] (stride 144B -> 2-way-free pfr
// reads). lsum: cross-wave (w,w+4) merge via 1KB LDS in epilogue. LDS 147KB
// -> 1 block/CU = 8 waves (same as before).
// Kept: XCD swizzle, f-split HS, no atomics, setprio, exp2 prescale, raw
// lgkm mid-barrier (no vmcnt drain — prefetch DMA stays in flight).
template<int HS>
__global__ __launch_bounds__(512, 2) void attn_k(
    const bf16* __restrict__ X, const bf16* __restrict__ QK, const bf16* __restrict__ Vt,
    const int* __restrict__ mask, const int* __restrict__ flags,
    bf16* __restrict__ Part, float* __restrict__ Lsum)
{
  __shared__ bf16 Ks[2][64 * 256];     // 64 KB: K-tile [64 f][256 k], XOR-swz
  __shared__ bf16 Vs[2][256 * 64];     // 64 KB: V-tile [256 d][64 f], XOR-swz
  __shared__ bf16 Ps[128 * 72];        // 18 KB: P [128 s][64 f + 8 pad]
  __shared__ float Ls[8][32];          // per-wave row-sum partials
  // XCD-aware remap: i = xcd + 8*round; round = gh_sub*16 + st; gh = xcd + 8*gh_sub
  const int i  = blockIdx.x;
  const int x  = i & 7, rr = i >> 3;
  const int gh = x + 8 * (rr >> 4);            // HS: 0..95 = half*48 + g ; else 0..47
  const int st = rr & 15;                      // 128-row s-tile
  const int h  = HS ? (gh >= 48 ? 1 : 0) : 0;
  const int g  = gh - 48 * h;                  // 0..47 = b*12+n
  const int b  = g / 12, n = g % 12;
  const int f_beg = h * 1024;
  const int f_end = f_beg + (HS ? 1024 : 2048);
  const int t = threadIdx.x, w = t >> 6, l = t & 63;
  const int lane16 = l & 15, quad = l >> 4;
  const int wsg = w & 3;                        // s-group (32 rows) for QK
  const int wfh = w >> 2;                       // f-half (32 cols) for QK
  const int sw = (st << 7) + (wsg << 5);        // wave's first of 32 s-rows
  const bf16* Xb = X + (size_t)b * S_ * D_;
  bf16x8 qf[2][8];                              // Q frags (B operand): 2 s-tiles x 256 k
#pragma unroll
  for (int ts = 0; ts < 2; ++ts)
#pragma unroll
    for (int kt = 0; kt < 8; ++kt)
      qf[ts][kt] = *(const bf16x8*)(Xb + (size_t)(sw + ts * 16 + lane16) * D_ + kt * 32 + quad * 8);
  const bf16* QKb = QK + (size_t)b * S_ * J_ + n * D_;
  const bf16* Vtb = Vt + (size_t)n * D_ * M_ + (size_t)b * S_;
  // flags row for this wave's 64-row s-group: st*2 + (wsg>>1)
  const int* flagb = flags + (b * 32 + st * 2 + (wsg >> 1)) * 32;
  f32x4 oacc[8][2] = {};                        // O[128s][32d]: [stile][dtile]
  float lsum[2] = {0.f, 0.f};                   // per-lane partial row sums (s=lane16)

  // staging helper: loads f-tile [f0, f0+64) into buffer `buf`
  auto stage = [&](int buf, int f0) {
#pragma unroll
    for (int ii = 0; ii < 4; ++ii) {
      int frow = ii * 16 + (t >> 5);
      int dc = (t & 31) ^ (frow & 7);
      g2lds16(&Ks[buf][ii * 4096 + (w << 9)], QKb + (size_t)(f0 + frow) * J_ + dc * 8);
    }
#pragma unroll
    for (int ii = 0; ii < 4; ++ii) {
      int drow = ii * 64 + (t >> 3);
      int fc = (t & 7) ^ (drow & 7);
      g2lds16(&Vs[buf][ii * 4096 + (w << 9)], Vtb + (size_t)drow * M_ + f0 + fc * 8);
    }
  };

  stage(0, f_beg);                              // prologue prefetch
  int cur = 0;
  for (int f0 = f_beg; f0 < f_end; f0 += 64) {
    __syncthreads();       // drains DMA(cur) (issued a full iter ago); buf cur^1 free
    if (f0 + 64 < f_end) stage(cur ^ 1, f0 + 64);  // prefetch next tile under compute
    // St = K Q^T : wave computes 32s (wsg) x 32f (wfh). C col=lane16=s,
    // row=quad*4+r=f-within-16. A=kf (rows f), B=qf.
    f32x4 sfr[2][2] = {};                       // [ts][ct]
    __builtin_amdgcn_s_setprio(1);
#pragma unroll
    for (int kt = 0; kt < 8; ++kt)
#pragma unroll
      for (int ct = 0; ct < 2; ++ct) {
        int fl = (wfh << 5) + ct * 16 + lane16; // A m-index rows f (0..63)
        bf16x8 kf = *(const bf16x8*)(&Ks[cur][fl * 256 + (((kt * 4 + quad) ^ (fl & 7)) * 8)]);
        sfr[0][ct] = MFMA16(kf, qf[0][kt], sfr[0][ct]);
        sfr[1][ct] = MFMA16(kf, qf[1][kt], sfr[1][ct]);
      }
    __builtin_amdgcn_s_setprio(0);
    // sfr[ts][ct][r] = St(s = sw+ts*16+lane16, f = f0+wfh*32+ct*16+quad*4+r)
    float ex[2][2][4];
    if (flagb[f0 >> 6]) {
#pragma unroll
      for (int ts = 0; ts < 2; ++ts)
#pragma unroll
        for (int ct = 0; ct < 2; ++ct)
#pragma unroll
          for (int r = 0; r < 4; ++r)
            ex[ts][ct][r] = __builtin_amdgcn_exp2f(sfr[ts][ct][r]);
    } else {
#pragma unroll
      for (int ts = 0; ts < 2; ++ts)
#pragma unroll
        for (int ct = 0; ct < 2; ++ct)
#pragma unroll
          for (int r = 0; r < 4; ++r) {
            int s = sw + ts * 16 + lane16;
            int f = f0 + (wfh << 5) + ct * 16 + quad * 4 + r;
            float add = (1.0f - (float)mask[(size_t)b * S_ * S_ + (size_t)s * S_ + f])
                        * (-10000.0f * LOG2E_);
            ex[ts][ct][r] = __builtin_amdgcn_exp2f(sfr[ts][ct][r] + add);
          }
    }
#pragma unroll
    for (int ts = 0; ts < 2; ++ts)
      lsum[ts] += ex[ts][0][0] + ex[ts][0][1] + ex[ts][0][2] + ex[ts][0][3]
                + ex[ts][1][0] + ex[ts][1][1] + ex[ts][1][2] + ex[ts][1][3];
    // P -> block-shared LDS [s][f] (A-operand orientation), 4 ds_write_b64/lane
#pragma unroll
    for (int ts = 0; ts < 2; ++ts)
#pragma unroll
      for (int ct = 0; ct < 2; ++ct) {
        int base = ((wsg << 5) + ts * 16 + lane16) * 72 + (wfh << 5) + ct * 16 + quad * 4;
        bf16x4 pv;
        pv[0] = (bf16)ex[ts][ct][0]; pv[1] = (bf16)ex[ts][ct][1];
        pv[2] = (bf16)ex[ts][ct][2]; pv[3] = (bf16)ex[ts][ct][3];
        *(bf16x4*)(&Ps[base]) = pv;
      }
    // publish Ps + barrier; NO vmcnt drain — prefetch DMA stays in flight.
    asm volatile("s_waitcnt lgkmcnt(0)\n\ts_barrier" ::: "memory");
    // PV d-split: wave owns d in [32w, 32w+32) for ALL 128 block s-rows.
    // vfr AFTER barrier (R18 lesson). vfr[dtile][kchunk], pfr pairs by kchunk.
    bf16x8 vfr[2][2];
#pragma unroll
    for (int dtile = 0; dtile < 2; ++dtile)
#pragma unroll
      for (int kc = 0; kc < 2; ++kc) {
        int dl = (w << 5) + dtile * 16 + lane16;
        vfr[dtile][kc] = *(const bf16x8*)(&Vs[cur][dl * 64 + (((kc * 4 + quad) ^ (dl & 7)) * 8)]);
      }
    __builtin_amdgcn_s_setprio(1);
#pragma unroll
    for (int stile = 0; stile < 8; ++stile) {
      const bf16* prow = &Ps[(stile * 16 + lane16) * 72 + quad * 8];
      bf16x8 pf0 = *(const bf16x8*)(prow);
      bf16x8 pf1 = *(const bf16x8*)(prow + 32);
      oacc[stile][0] = MFMA16(pf0, vfr[0][0], oacc[stile][0]);
      oacc[stile][0] = MFMA16(pf1, vfr[0][1], oacc[stile][0]);
      oacc[stile][1] = MFMA16(pf0, vfr[1][0], oacc[stile][1]);
      oacc[stile][1] = MFMA16(pf1, vfr[1][1], oacc[stile][1]);
    }
    __builtin_amdgcn_s_setprio(0);
    cur ^= 1;
  }
  // finalize row sums: quad-reduce within wave, then merge f-halves (w, w+4)
  float tot[2];
#pragma unroll
  for (int ts = 0; ts < 2; ++ts) {
    float rs = lsum[ts];
    rs += __shfl_xor(rs, 16);
    rs += __shfl_xor(rs, 32);
    tot[ts] = rs;                               // lane: wave-partial for s=ts*16+lane16
  }
  if (l < 16) {
#pragma unroll
    for (int ts = 0; ts < 2; ++ts) Ls[w][ts * 16 + l] = tot[ts];
  }
  __syncthreads();
  // write UN-normalized partial context (bf16) + row sums — exclusive writer
  bf16*  Cb = Part + (size_t)(h * 48 + g) * S_ * D_;
  float* Lb = Lsum + (size_t)(h * 48 + g) * S_;
  if (w < 4 && l < 16) {                        // s-group w, merged over f-halves
#pragma unroll
    for (int ts = 0; ts < 2; ++ts)
      Lb[(st << 7) + (w << 5) + ts * 16 + l] = Ls[w][ts * 16 + l] + Ls[w + 4][ts * 16 + l];
  }
  // O epilogue: s = st*128 + stile*16 + quad*4 + r, d = w*32 + dtile*16 + lane16
#pragma unroll
  for (int stile = 0; stile < 8; ++stile)
#pragma unroll
    for (int r = 0; r < 4; ++r) {
      int s = (st << 7) + stile * 16 + quad * 4 + r;
#pragma unroll
      for (int dtile = 0; dtile < 2; ++dtile) {
        int d = (w << 5) + dtile * 16 + lane16;
        Cb[(size_t)s * D_ + d] = (bf16)oacc[stile][dtile][r];
      }
    }
}

// ------- head sum: out[b,s,d] = sum_n (P0+P1)[b,n,s,d] / (l0+l1)[b,n,s] -------
template<int HS>
__global__ __launch_bounds__(256) void head_sum(const bf16* __restrict__ Part,
                                                const float* __restrict__ Lsum,
                                                float* __restrict__ out) {
  int i = blockIdx.x * 256 + threadIdx.x;
  int m = i >> 5;                      // flattened row 0..8191
  int dc = (i & 31) * 8;               // d-chunk
  int b = m >> 11, s = m & 2047;
  float acc[8] = {};
#pragma unroll
  for (int n = 0; n < NH_; ++n) {
    int g = b * NH_ + n;
    const bf16* p = Part + ((size_t)g * S_ + s) * D_ + dc;
    float lv = Lsum[(size_t)g * S_ + s];
    bf16x8 v0 = *(const bf16x8*)p;
    float a[8];
#pragma unroll
    for (int k = 0; k < 8; ++k) a[k] = (float)v0[k];
    if (HS) {
      lv += Lsum[(size_t)(48 + g) * S_ + s];
      bf16x8 v1 = *(const bf16x8*)(p + (size_t)48 * S_ * D_);
#pragma unroll
      for (int k = 0; k < 8; ++k) a[k] += (float)v1[k];
    }
    float inv = 1.0f / lv;
#pragma unroll
    for (int k = 0; k < 8; ++k) acc[k] += a[k] * inv;
  }
  f32x4 o0, o1;
#pragma unroll
  for (int k = 0; k < 4; ++k) { o0[k] = acc[k]; o1[k] = acc[4 + k]; }
  float* q = out + (size_t)m * D_ + dc;
  *(f32x4*)q = o0;
  *(f32x4*)(q + 4) = o1;
}

extern "C" void kernel_launch(void* const* d_in, const int* in_sizes, int n_in,
                              void* d_out, int out_size, void* d_ws, size_t ws_size,
                              hipStream_t stream) {
  (void)in_sizes; (void)n_in; (void)out_size;
  const float* X    = (const float*)d_in[0];   // fp32 per reference
  const int*   mask = (const int*)d_in[1];
  const float* Wqk  = (const float*)d_in[2];
  const float* bqk  = (const float*)d_in[3];
  const float* Wv   = (const float*)d_in[4];
  const float* bv   = (const float*)d_in[5];
  float* out = (float*)d_out;                  // fp32 per reference output

  char* p = (char*)d_ws;
  bf16*  Xbf  = (bf16*)p;  p += (size_t)M_ * D_ * 2;      // 4.2 MB
  bf16*  Wqkt = (bf16*)p;  p += (size_t)J_ * D_ * 2;      // 1.5 MB
  bf16*  Wvt  = (bf16*)p;  p += (size_t)J_ * D_ * 2;      // 1.5 MB
  bf16*  QKw  = (bf16*)p;  p += (size_t)M_ * J_ * 2;      // 50.3 MB  [m][j]
  bf16*  Vtw  = (bf16*)p;  p += (size_t)J_ * M_ * 2;      // 50.3 MB  [j][m]
  int*   flags= (int*)p;   p += 4096 * 4;                 // 16 KB
  float* Lsum = (float*)p; p += (size_t)2 * 48 * S_ * 4;  // 0.8 MB [h][g][s]
  bf16*  Part = (bf16*)p;                                 // [h][g][s][d]
  size_t need = (size_t)(p - (char*)d_ws) + (size_t)2 * 48 * S_ * D_ * 2; // ~209.5 MB
  int hs = (ws_size >= need) ? 1 : 0;          // fall back to unsplit if ws too small

  prep_k<<<2048 + 384, 256, 0, stream>>>(X, Xbf, Wqk, Wqkt, Wv, Wvt);
  gemm_flags<<<3072 + 4096, 256, 0, stream>>>(Xbf, Wqkt, bqk, QKw, Wvt, bv, Vtw,
                                              mask, flags);
  if (hs) {
    attn_k<1><<<B_ * NH_ * (S_ / 128) * 2, 512, 0, stream>>>(Xbf, QKw, Vtw, mask, flags, Part, Lsum);
    head_sum<1><<<(M_ * D_ / 8) / 256, 256, 0, stream>>>(Part, Lsum, out);
  } else {
    attn_k<0><<<B_ * NH_ * (S_ / 128), 512, 0, stream>>>(Xbf, QKw, Vtw, mask, flags, Part, Lsum);
    head_sum<0><<<(M_ * D_ / 8) / 256, 256, 0, stream>>>(Part, Lsum, out);
  }
}

// Round 13
// 395.223 us; speedup vs baseline: 1.1284x; 1.1284x over previous
//
#include <hip/hip_runtime.h>
#include <stdint.h>

#define B_ 4
#define S_ 2048
#define D_ 256
#define NH_ 12
#define M_ (B_*S_)      // 8192 rows of flattened input
#define J_ (NH_*D_)     // 3072 projection cols
#define LOG2E_ 1.4426950408889634f

typedef __bf16 bf16;
typedef __bf16 bf16x8 __attribute__((ext_vector_type(8)));
typedef __bf16 bf16x4 __attribute__((ext_vector_type(4)));
typedef float  f32x4  __attribute__((ext_vector_type(4)));

#define MFMA16(a,b,c) __builtin_amdgcn_mfma_f32_16x16x32_bf16(a,b,c,0,0,0)

__device__ __forceinline__ void g2lds16(void* l, const void* g) {
  __builtin_amdgcn_global_load_lds(
      (const __attribute__((address_space(1))) unsigned int*)g,
      (__attribute__((address_space(3))) unsigned int*)l, 16, 0, 0);
}

// ---------- prep: X fp32->bf16 (blocks 0..2047) + weight transpose (2048..2431) ----------
__global__ __launch_bounds__(256) void prep_k(const float* __restrict__ X,
                                              bf16* __restrict__ Xbf,
                                              const float* __restrict__ Wqk,
                                              bf16* __restrict__ Wqkt,
                                              const float* __restrict__ Wv,
                                              bf16* __restrict__ Wvt) {
  int bid = blockIdx.x;
  if (bid < 2048) {
    int i = bid * 256 + threadIdx.x;
    f32x4 v = *(const f32x4*)(X + (size_t)i * 4);
    bf16x4 o;
#pragma unroll
    for (int k = 0; k < 4; ++k) o[k] = (bf16)v[k];
    *(bf16x4*)(Xbf + (size_t)i * 4) = o;
  } else {
    int q = bid - 2048;                        // 0..383 = z*192 + y*12 + x
    const float* W = (q >= 192) ? Wv : Wqk;
    bf16* Wt       = (q >= 192) ? Wvt : Wqkt;
    q %= 192;
    int c0 = (q / 12) * 16;
    int j  = (q % 12) * 256 + threadIdx.x;     // coalesced over j
    bf16x8 v0, v1;
#pragma unroll
    for (int i = 0; i < 8; ++i) v0[i] = (bf16)W[(size_t)(c0 + i) * J_ + j];
#pragma unroll
    for (int i = 0; i < 8; ++i) v1[i] = (bf16)W[(size_t)(c0 + 8 + i) * J_ + j];
    *(bf16x8*)(Wt + (size_t)j * D_ + c0)     = v0;
    *(bf16x8*)(Wt + (size_t)j * D_ + c0 + 8) = v1;
  }
}

// ---------------- mask tile flags body: 1 if 64x64 tile is all ones ----------------
__device__ __forceinline__ void mask_flags_body(const int* __restrict__ mask,
                                                int* __restrict__ flags, int bx) {
  int ft = bx & 31, st = (bx >> 5) & 31, b = bx >> 10;
  int t = threadIdx.x;
  const int4* mp4 = (const int4*)(mask + (size_t)b * S_ * S_ +
                                  (size_t)(st * 64 + (t >> 2)) * S_ + ft * 64 + (t & 3) * 16);
  bool ok = true;
#pragma unroll
  for (int i = 0; i < 4; ++i) {
    int4 v = mp4[i];
    ok &= (v.x == 1) & (v.y == 1) & (v.z == 1) & (v.w == 1);
  }
  __shared__ int flag;
  if (t == 0) flag = 1;
  __syncthreads();
  if (!ok) flag = 0;                   // benign race, all write 0
  __syncthreads();
  if (t == 0) flags[bx] = flag;
}

// ---------------- GEMM body: C[M][N] = (A[M][256] * Bm[N][256]^T + bias)*scale --------
// 128x128 tile, BK=64, 4 waves each 64x64. XOR 8-chunk swizzle -> 2-way banks.
// R15: double-buffered LDS + 1-iter prefetch. R18: scale folds log2e for QK.
__device__ __forceinline__ void gemm_body(
    const bf16* __restrict__ A, const bf16* __restrict__ Bm,
    const float* __restrict__ bias, bf16* __restrict__ C,
    int Ndim, int bias_mode, float scale, int bid)
{
  __shared__ bf16 As[2][128 * 64];
  __shared__ bf16 Bs[2][128 * 64];
  const int nbn = Ndim >> 7;
  const int bm = bid / nbn, bn = bid % nbn;
  const int t = threadIdx.x, w = t >> 6, l = t & 63;
  const int lane16 = l & 15, quad = l >> 4;
  const int wm = (w & 1) << 6, wn = (w >> 1) << 6;
  const int srow = t >> 3;
  const int gc = (t & 7) ^ (srow & 7);
  const bf16* Ag = A + (size_t)((bm << 7) + srow) * 256 + gc * 8;
  const bf16* Bg = Bm + (size_t)((bn << 7) + srow) * 256 + gc * 8;

  auto stage = [&](int buf, int k0) {
#pragma unroll
    for (int i = 0; i < 4; ++i)
      g2lds16(&As[buf][(size_t)(i * 256 + (w << 6)) * 8], Ag + (size_t)i * 32 * 256 + k0);
#pragma unroll
    for (int i = 0; i < 4; ++i)
      g2lds16(&Bs[buf][(size_t)(i * 256 + (w << 6)) * 8], Bg + (size_t)i * 32 * 256 + k0);
  };

  f32x4 acc[4][4] = {};
  stage(0, 0);                          // prologue prefetch
  int cur = 0;
  for (int k0 = 0; k0 < 256; k0 += 64) {
    __syncthreads();                    // drains DMA(cur) issued one iter ago
    if (k0 + 64 < 256) stage(cur ^ 1, k0 + 64);  // prefetch under compute
#pragma unroll
    for (int kt = 0; kt < 2; ++kt) {
      bf16x8 af[4], bfr[4];
#pragma unroll
      for (int i = 0; i < 4; ++i)
        af[i] = *(const bf16x8*)(&As[cur][(wm + i * 16 + lane16) * 64 +
                                 (((kt * 4 + quad) ^ (lane16 & 7)) * 8)]);
#pragma unroll
      for (int i = 0; i < 4; ++i)
        bfr[i] = *(const bf16x8*)(&Bs[cur][(wn + i * 16 + lane16) * 64 +
                                  (((kt * 4 + quad) ^ (lane16 & 7)) * 8)]);
#pragma unroll
      for (int i = 0; i < 4; ++i)
#pragma unroll
        for (int jx = 0; jx < 4; ++jx)
          acc[i][jx] = MFMA16(af[i], bfr[jx], acc[i][jx]);
    }
    cur ^= 1;
  }
#pragma unroll
  for (int i = 0; i < 4; ++i)
#pragma unroll
    for (int jx = 0; jx < 4; ++jx) {
      int col = (bn << 7) + wn + jx * 16 + lane16;
#pragma unroll
      for (int r = 0; r < 4; ++r) {
        int row = (bm << 7) + wm + i * 16 + quad * 4 + r;
        float v = (acc[i][jx][r] + (bias_mode ? bias[row] : bias[col])) * scale;
        C[(size_t)row * Ndim + col] = (bf16)v;
      }
    }
}

// R17: both projections + mask_flags in ONE dispatch.
__global__ __launch_bounds__(256) void gemm_flags(
    const bf16* __restrict__ Xbf, const bf16* __restrict__ Wqkt,
    const float* __restrict__ bqk, bf16* __restrict__ QKw,
    const bf16* __restrict__ Wvt, const float* __restrict__ bv,
    bf16* __restrict__ Vtw,
    const int* __restrict__ mask, int* __restrict__ flags)
{
  int bid = blockIdx.x;
  if (bid < 1536)      gemm_body(Xbf, Wqkt, bqk, QKw, J_, 0, LOG2E_, bid);
  else if (bid < 3072) gemm_body(Wvt, Xbf, bv, Vtw, M_, 1, 1.0f, bid - 1536);
  else                 mask_flags_body(mask, flags, bid - 3072);
}

// ---------------- fused attention (R9 final form — session best) ----------------
// XCD-swizzled grid. 2 blocks/CU of 4 waves each; wave owns 32 s-rows for QK.
// TRANSPOSED QK (A=K-frag, B=Q-frag). K/V double-buffered in LDS.
// STRUCTURAL FLOOR (R12 conclusion): ~256us is latency-bound with no pipe
// >50%. All levers tested: occupancy register-pinned (128V+128A = exactly
// 2 waves/SIMD; R6 LDS cut -> no occupancy gain, global-V scatter 385us);
// LDS-byte cut -14% -> -1% (R5); 8-wave KVBLK=64 block -> 291us (R12:
// barrier then idles WHOLE CU; two 4-wave blocks interleave barrier waits —
// independent blocks ARE the latency hiding); exp2f libm bloat (R8) fixed
// via __builtin_amdgcn_exp2f (R9); vfr hoist above lgkm barrier serializes
// (R8). Keep: f-split HS (R14), no atomics (R13), setprio (R15), PV d-split
// + raw lgkm mid-barrier (R16), log2e prescale (R19).
template<int HS>
__global__ __launch_bounds__(256, 2) void attn_k(
    const bf16* __restrict__ X, const bf16* __restrict__ QK, const bf16* __restrict__ Vt,
    const int* __restrict__ mask, const int* __restrict__ flags,
    bf16* __restrict__ Part, float* __restrict__ Lsum)
{
  __shared__ bf16 Ks[2][32 * 256];
  __shared__ bf16 Vs[2][256 * 32];
  __shared__ bf16 Ps[4][32 * 40];
  // XCD-aware remap: i = xcd + 8*round; round = gh_sub*16 + st; gh = xcd + 8*gh_sub
  const int i  = blockIdx.x;
  const int x  = i & 7, rr = i >> 3;
  const int gh = x + 8 * (rr >> 4);            // HS: 0..95 = half*48 + g ; else 0..47
  const int st = rr & 15;                      // 128-row s-tile
  const int h  = HS ? (gh >= 48 ? 1 : 0) : 0;
  const int g  = gh - 48 * h;                  // 0..47 = b*12+n
  const int b  = g / 12, n = g % 12;
  const int f_beg = h * 1024;
  const int f_end = f_beg + (HS ? 1024 : 2048);
  const int t = threadIdx.x, w = t >> 6, l = t & 63;
  const int lane16 = l & 15, quad = l >> 4;
  const int sw = (st << 7) + (w << 5);          // wave's first of 32 s-rows (QK phase)
  const bf16* Xb = X + (size_t)b * S_ * D_;
  bf16x8 qf[2][8];                              // Q frags (B operand): 2 s-tiles x 256 k
#pragma unroll
  for (int ts = 0; ts < 2; ++ts)
#pragma unroll
    for (int kt = 0; kt < 8; ++kt)
      qf[ts][kt] = *(const bf16x8*)(Xb + (size_t)(sw + ts * 16 + lane16) * D_ + kt * 32 + quad * 8);
  const bf16* QKb = QK + (size_t)b * S_ * J_ + n * D_;
  const bf16* Vtb = Vt + (size_t)n * D_ * M_ + (size_t)b * S_;
  // flags row for this wave's 64-row tile: st*2 + (w>>1); f-index is absolute
  const int* flagb = flags + (b * 32 + st * 2 + (w >> 1)) * 32;
  f32x4 oacc[8][4] = {};                        // O[128s][64d]: [stile][dtile], d-split
  float lsum[2] = {0.f, 0.f};                   // per-lane partial row sums (s=lane16)

  // staging helper: loads f-tile f0 into buffer `buf`
  auto stage = [&](int buf, int f0) {
#pragma unroll
    for (int ii = 0; ii < 4; ++ii) {
      int frow = ii * 8 + (t >> 5);
      int dc = (t & 31) ^ (frow & 7);
      g2lds16(&Ks[buf][ii * 2048 + (w << 9)], QKb + (size_t)(f0 + frow) * J_ + dc * 8);
    }
#pragma unroll
    for (int ii = 0; ii < 4; ++ii) {
      int drow = ii * 64 + (t >> 2);
      int fc = (t & 3) ^ ((drow >> 1) & 3);
      g2lds16(&Vs[buf][ii * 2048 + (w << 9)], Vtb + (size_t)drow * M_ + f0 + fc * 8);
    }
  };

  stage(0, f_beg);                              // prologue prefetch
  int cur = 0;
  for (int f0 = f_beg; f0 < f_end; f0 += 32) {
    __syncthreads();       // drains DMA(cur) (issued a full iter ago); buf cur^1 free
    if (f0 + 32 < f_end) stage(cur ^ 1, f0 + 32);  // prefetch next tile under compute
    // St = K Q^T : C-layout col=lane16=s, row=quad*4+r=f.  A=kf, B=qf.
    f32x4 sfr[2][2] = {};                       // [ts][ct]
    __builtin_amdgcn_s_setprio(1);
#pragma unroll
    for (int kt = 0; kt < 8; ++kt)
#pragma unroll
      for (int ct = 0; ct < 2; ++ct) {
        int fl = ct * 16 + lane16;              // A m-index rows f
        bf16x8 kf = *(const bf16x8*)(&Ks[cur][fl * 256 + (((kt * 4 + quad) ^ (fl & 7)) * 8)]);
        sfr[0][ct] = MFMA16(kf, qf[0][kt], sfr[0][ct]);
        sfr[1][ct] = MFMA16(kf, qf[1][kt], sfr[1][ct]);
      }
    __builtin_amdgcn_s_setprio(0);
    // sfr is pre-scaled by log2e (GEMM epilogue) -> raw v_exp_f32
    float ex[2][2][4];
    if (flagb[f0 >> 6]) {
#pragma unroll
      for (int ts = 0; ts < 2; ++ts)
#pragma unroll
        for (int ct = 0; ct < 2; ++ct)
#pragma unroll
          for (int r = 0; r < 4; ++r)
            ex[ts][ct][r] = __builtin_amdgcn_exp2f(sfr[ts][ct][r]);
    } else {
#pragma unroll
      for (int ts = 0; ts < 2; ++ts)
#pragma unroll
        for (int ct = 0; ct < 2; ++ct)
#pragma unroll
          for (int r = 0; r < 4; ++r) {
            int s = sw + ts * 16 + lane16, f = f0 + ct * 16 + quad * 4 + r;
            float add = (1.0f - (float)mask[(size_t)b * S_ * S_ + (size_t)s * S_ + f])
                        * (-10000.0f * LOG2E_);
            ex[ts][ct][r] = __builtin_amdgcn_exp2f(sfr[ts][ct][r] + add);
          }
    }
#pragma unroll
    for (int ts = 0; ts < 2; ++ts)
      lsum[ts] += ex[ts][0][0] + ex[ts][0][1] + ex[ts][0][2] + ex[ts][0][3]
                + ex[ts][1][0] + ex[ts][1][1] + ex[ts][1][2] + ex[ts][1][3];
    // P -> LDS in A-operand orientation [s=row][f=col], 4 ds_write_b64 per wave
#pragma unroll
    for (int ts = 0; ts < 2; ++ts)
#pragma unroll
      for (int ct = 0; ct < 2; ++ct) {
        int base = (ts * 16 + lane16) * 40 + ct * 16 + quad * 4;
        bf16x4 pv;
        pv[0] = (bf16)ex[ts][ct][0]; pv[1] = (bf16)ex[ts][ct][1];
        pv[2] = (bf16)ex[ts][ct][2]; pv[3] = (bf16)ex[ts][ct][3];
        *(bf16x4*)(&Ps[w][base]) = pv;
      }
    // Ps is BLOCK-shared: publish writes + barrier, but do NOT drain vmcnt —
    // the K/V prefetch DMA must stay in flight.
    asm volatile("s_waitcnt lgkmcnt(0)\n\ts_barrier" ::: "memory");
    // PV d-split: wave owns d in [64w, 64w+64) for ALL 128 block s-rows.
    // vfr reads AFTER the barrier (R18 lesson: hoisting serializes them into
    // the barrier wait; here they overlap other waves' PV).
    bf16x8 vfr[4];
#pragma unroll
    for (int dtile = 0; dtile < 4; ++dtile) {
      int dl = (w << 6) + dtile * 16 + lane16;
      vfr[dtile] = *(const bf16x8*)(&Vs[cur][dl * 32 + ((quad ^ ((dl >> 1) & 3)) * 8)]);
    }
    __builtin_amdgcn_s_setprio(1);
#pragma unroll
    for (int stile = 0; stile < 8; ++stile) {
      bf16x8 pfr = *(const bf16x8*)(&Ps[stile >> 1][(((stile & 1) << 4) + lane16) * 40 + quad * 8]);
#pragma unroll
      for (int dtile = 0; dtile < 4; ++dtile)
        oacc[stile][dtile] = MFMA16(pfr, vfr[dtile], oacc[stile][dtile]);
    }
    __builtin_amdgcn_s_setprio(0);
    cur ^= 1;
  }
  // finalize row sums: reduce across quads (lanes s, s+16, s+32, s+48)
  float tot[2];
#pragma unroll
  for (int ts = 0; ts < 2; ++ts) {
    float rs = lsum[ts];
    rs += __shfl_xor(rs, 16);
    rs += __shfl_xor(rs, 32);
    tot[ts] = rs;                               // every lane: total for s=ts*16+lane16
  }
  // write UN-normalized partial context (bf16) + row sums — exclusive writer
  bf16*  Cb = Part + (size_t)(h * 48 + g) * S_ * D_;
  float* Lb = Lsum + (size_t)(h * 48 + g) * S_;
  if (l < 16) {                                 // quad==0 lanes hold s = ts*16 + l
#pragma unroll
    for (int ts = 0; ts < 2; ++ts) Lb[sw + ts * 16 + l] = tot[ts];
  }
  // O epilogue (d-split layout): s = st*128 + stile*16 + quad*4 + r,
  // d = w*64 + dtile*16 + lane16
#pragma unroll
  for (int stile = 0; stile < 8; ++stile)
#pragma unroll
    for (int r = 0; r < 4; ++r) {
      int s = (st << 7) + stile * 16 + quad * 4 + r;
#pragma unroll
      for (int dtile = 0; dtile < 4; ++dtile) {
        int d = (w << 6) + dtile * 16 + lane16;
        Cb[(size_t)s * D_ + d] = (bf16)oacc[stile][dtile][r];
      }
    }
}

// ------- head sum: out[b,s,d] = sum_n (P0+P1)[b,n,s,d] / (l0+l1)[b,n,s] -------
template<int HS>
__global__ __launch_bounds__(256) void head_sum(const bf16* __restrict__ Part,
                                                const float* __restrict__ Lsum,
                                                float* __restrict__ out) {
  int i = blockIdx.x * 256 + threadIdx.x;
  int m = i >> 5;                      // flattened row 0..8191
  int dc = (i & 31) * 8;               // d-chunk
  int b = m >> 11, s = m & 2047;
  float acc[8] = {};
#pragma unroll
  for (int n = 0; n < NH_; ++n) {
    int g = b * NH_ + n;
    const bf16* p = Part + ((size_t)g * S_ + s) * D_ + dc;
    float lv = Lsum[(size_t)g * S_ + s];
    bf16x8 v0 = *(const bf16x8*)p;
    float a[8];
#pragma unroll
    for (int k = 0; k < 8; ++k) a[k] = (float)v0[k];
    if (HS) {
      lv += Lsum[(size_t)(48 + g) * S_ + s];
      bf16x8 v1 = *(const bf16x8*)(p + (size_t)48 * S_ * D_);
#pragma unroll
      for (int k = 0; k < 8; ++k) a[k] += (float)v1[k];
    }
    float inv = 1.0f / lv;
#pragma unroll
    for (int k = 0; k < 8; ++k) acc[k] += a[k] * inv;
  }
  f32x4 o0, o1;
#pragma unroll
  for (int k = 0; k < 4; ++k) { o0[k] = acc[k]; o1[k] = acc[4 + k]; }
  float* q = out + (size_t)m * D_ + dc;
  *(f32x4*)q = o0;
  *(f32x4*)(q + 4) = o1;
}

extern "C" void kernel_launch(void* const* d_in, const int* in_sizes, int n_in,
                              void* d_out, int out_size, void* d_ws, size_t ws_size,
                              hipStream_t stream) {
  (void)in_sizes; (void)n_in; (void)out_size;
  const float* X    = (const float*)d_in[0];   // fp32 per reference
  const int*   mask = (const int*)d_in[1];
  const float* Wqk  = (const float*)d_in[2];
  const float* bqk  = (const float*)d_in[3];
  const float* Wv   = (const float*)d_in[4];
  const float* bv   = (const float*)d_in[5];
  float* out = (float*)d_out;                  // fp32 per reference output

  char* p = (char*)d_ws;
  bf16*  Xbf  = (bf16*)p;  p += (size_t)M_ * D_ * 2;      // 4.2 MB
  bf16*  Wqkt = (bf16*)p;  p += (size_t)J_ * D_ * 2;      // 1.5 MB
  bf16*  Wvt  = (bf16*)p;  p += (size_t)J_ * D_ * 2;      // 1.5 MB
  bf16*  QKw  = (bf16*)p;  p += (size_t)M_ * J_ * 2;      // 50.3 MB  [m][j]
  bf16*  Vtw  = (bf16*)p;  p += (size_t)J_ * M_ * 2;      // 50.3 MB  [j][m]
  int*   flags= (int*)p;   p += 4096 * 4;                 // 16 KB
  float* Lsum = (float*)p; p += (size_t)2 * 48 * S_ * 4;  // 0.8 MB [h][g][s]
  bf16*  Part = (bf16*)p;                                 // [h][g][s][d]
  size_t need = (size_t)(p - (char*)d_ws) + (size_t)2 * 48 * S_ * D_ * 2; // ~209.5 MB
  int hs = (ws_size >= need) ? 1 : 0;          // fall back to unsplit if ws too small

  prep_k<<<2048 + 384, 256, 0, stream>>>(X, Xbf, Wqk, Wqkt, Wv, Wvt);
  gemm_flags<<<3072 + 4096, 256, 0, stream>>>(Xbf, Wqkt, bqk, QKw, Wvt, bv, Vtw,
                                              mask, flags);
  if (hs) {
    attn_k<1><<<B_ * NH_ * (S_ / 128) * 2, 256, 0, stream>>>(Xbf, QKw, Vtw, mask, flags, Part, Lsum);
    head_sum<1><<<(M_ * D_ / 8) / 256, 256, 0, stream>>>(Part, Lsum, out);
  } else {
    attn_k<0><<<B_ * NH_ * (S_ / 128), 256, 0, stream>>>(Xbf, QKw, Vtw, mask, flags, Part, Lsum);
    head_sum<0><<<(M_ * D_ / 8) / 256, 256, 0, stream>>>(Part, Lsum, out);
  }
}